// Round 12
// baseline (805.525 us; speedup 1.0000x reference)
//
#include <hip/hip_runtime.h>
#include <hip/hip_bf16.h>

#define NEG_SLOPE 0.2f

typedef __attribute__((ext_vector_type(8))) short bf16x8;
typedef __attribute__((ext_vector_type(4))) float f32x4;

__device__ __forceinline__ float bf2f(unsigned short u) {
    return __uint_as_float((unsigned)u << 16);
}
__device__ __forceinline__ unsigned short f2bf(float f) {
    unsigned b = __float_as_uint(f);
    return (unsigned short)((b + 0x7FFFu + ((b >> 16) & 1u)) >> 16);
}

// ---------- CSR build ----------
__global__ void k_hist(const int* __restrict__ dst, int E, int* __restrict__ deg) {
    int e = blockIdx.x * 256 + threadIdx.x;
    if (e < E) atomicAdd(&deg[dst[e]], 1);
}

__global__ __launch_bounds__(1024) void k_scan_chunk(const int* __restrict__ deg,
                                                     int* __restrict__ start,
                                                     int* __restrict__ csum, int n) {
    __shared__ int wsum[16];
    const int lane = threadIdx.x & 63;
    const int w = threadIdx.x >> 6;
    int i = blockIdx.x * 1024 + (int)threadIdx.x;
    int v = (i < n) ? deg[i] : 0;
    int s = v;
#pragma unroll
    for (int o = 1; o < 64; o <<= 1) {
        int u = __shfl_up(s, o);
        if (lane >= o) s += u;
    }
    if (lane == 63) wsum[w] = s;
    __syncthreads();
    if (w == 0) {
        int ws = (lane < 16) ? wsum[lane] : 0;
#pragma unroll
        for (int o = 1; o < 16; o <<= 1) {
            int u = __shfl_up(ws, o);
            if (lane >= o) ws += u;
        }
        if (lane < 16) wsum[lane] = ws;
    }
    __syncthreads();
    int woff = (w == 0) ? 0 : wsum[w - 1];
    int incl = s + woff;
    if (i < n) start[i] = incl - v;
    if (threadIdx.x == 1023) csum[blockIdx.x] = incl;
}

__global__ void k_scan_top(int* __restrict__ csum, int nch, int* __restrict__ start, int n) {
    int t = threadIdx.x;
    int v = (t < nch) ? csum[t] : 0;
    int s = v;
#pragma unroll
    for (int o = 1; o < 64; o <<= 1) {
        int u = __shfl_up(s, o);
        if (t >= o) s += u;
    }
    if (t < nch) csum[t] = s - v;
    if (t == 63) start[n] = s;
}

__global__ void k_scan_apply(int* __restrict__ start, const int* __restrict__ csum, int n) {
    int i = blockIdx.x * 256 + threadIdx.x;
    if (i < n) start[i] += csum[i >> 10];
}

__global__ void k_fill(const int* __restrict__ src, const int* __restrict__ dst, int E,
                       const int* __restrict__ start, int* __restrict__ cursor,
                       int* __restrict__ perm, int* __restrict__ src_sorted,
                       int* __restrict__ sortpos) {
    int e = blockIdx.x * 256 + threadIdx.x;
    if (e >= E) return;
    int d = dst[e];
    int idx = start[d] + atomicAdd(&cursor[d], 1);
    perm[idx] = e;
    src_sorted[idx] = src[e];
    sortpos[e] = idx;
}

// ---------- self-loop attr: gather-side segment mean, 16 rows in flight ----------
__global__ __launch_bounds__(256) void k_loop_csr(
    const float* __restrict__ eattr, const int* __restrict__ perm,
    const int* __restrict__ start, float* __restrict__ loop_attr, int n) {
    int node = blockIdx.x * 4 + (threadIdx.x >> 6);
    int t = threadIdx.x & 63;
    if (node >= n) return;
    int a = start[node], b = start[node + 1];
    int g = t >> 3, gl = t & 7;
    float4 acc = make_float4(0.f, 0.f, 0.f, 0.f);
    int j = a + g;
    for (; j + 8 < b; j += 16) {
        int e1 = perm[j];
        int e2 = perm[j + 8];
        const float4 v1 = *(const float4*)&eattr[(size_t)e1 * 32 + gl * 4];
        const float4 v2 = *(const float4*)&eattr[(size_t)e2 * 32 + gl * 4];
        acc.x += v1.x + v2.x; acc.y += v1.y + v2.y;
        acc.z += v1.z + v2.z; acc.w += v1.w + v2.w;
    }
    if (j < b) {
        int e = perm[j];
        const float4 v = *(const float4*)&eattr[(size_t)e * 32 + gl * 4];
        acc.x += v.x; acc.y += v.y; acc.z += v.z; acc.w += v.w;
    }
#pragma unroll
    for (int mask = 8; mask <= 32; mask <<= 1) {
        acc.x += __shfl_xor(acc.x, mask);
        acc.y += __shfl_xor(acc.y, mask);
        acc.z += __shfl_xor(acc.z, mask);
        acc.w += __shfl_xor(acc.w, mask);
    }
    if (t < 8) {
        float deg = fmaxf((float)(b - a), 1.f);
        float4 o = make_float4(acc.x / deg, acc.y / deg, acc.z / deg, acc.w / deg);
        *(float4*)&loop_attr[(size_t)node * 32 + gl * 4] = o;
    }
}

// ---------- node transform: xl(fp32) + xlb,xrb(bf16 score tables) ----------
template <int DIN>
__global__ void k_node_transform(const float* __restrict__ h,
                                 const float* __restrict__ Wl, const float* __restrict__ bl,
                                 const float* __restrict__ Wr, const float* __restrict__ br,
                                 float* __restrict__ xl, unsigned short* __restrict__ xlb,
                                 unsigned short* __restrict__ xrb, int n) {
    __shared__ float hs[4][DIN];
    int node0 = blockIdx.x * 4;
    int tid = threadIdx.x;
    for (int idx = tid; idx < 4 * DIN; idx += 256) {
        int ln = idx / DIN, k = idx % DIN;
        int node = node0 + ln;
        hs[ln][k] = (node < n) ? h[(long long)node * DIN + k] : 0.f;
    }
    __syncthreads();
    int ln = tid >> 6;
    int j = tid & 63;
    int node = node0 + ln;
    if (node >= n) return;
    float al = bl[j], ar = br[j];
#pragma unroll 8
    for (int k = 0; k < DIN; ++k) {
        float hv = hs[ln][k];
        al += hv * Wl[k * 64 + j];
        ar += hv * Wr[k * 64 + j];
    }
    xl[(long long)node * 64 + j] = al;
    xlb[(long long)node * 64 + j] = f2bf(al);
    xrb[(long long)node * 64 + j] = f2bf(ar);
}

// ---------- phase A: MFMA edge scores ----------
// 128 edges/block, 4 waves. z^T[64ch x 128e] = We^T @ ea^T via 32x
// mfma_f32_16x16x32_bf16 (8/wave). ea staged in LDS in B-fragment order
// (consecutive 16B/lane, conflict-free); We A-frags from global (L2).
// Epilogue: C/D layout col=lane&15(edge), row=(lane>>4)*4+reg(channel);
// per-lane 4x8B bf16 xl/xr gathers; leaky+att dot; shfl_xor(16,32) reduce.
__global__ __launch_bounds__(256, 2) void k_edge_score(
    const unsigned short* __restrict__ xlb, const unsigned short* __restrict__ xrb,
    const float* __restrict__ eattr,
    const float* __restrict__ We, const float* __restrict__ att,
    const int* __restrict__ src, const int* __restrict__ dst,
    const int* __restrict__ sortpos, int E,
    float* __restrict__ ex_sorted) {
    __shared__ __align__(16) short ea_frag[4][128][8];  // [k-chunk][edge][8 bf16] = 8 KB
    __shared__ float att_s[64];
    __shared__ int s_s[128], d_s[128], sp_s[128];

    const int tid = threadIdx.x;
    const int ge0 = blockIdx.x * 128;

    if (tid < 128) {
        int ge = ge0 + tid;
        bool ok = ge < E;
        s_s[tid] = ok ? src[ge] : 0;
        d_s[tid] = ok ? dst[ge] : 0;
        sp_s[tid] = ok ? sortpos[ge] : 0;
    }
    if (tid >= 128 && tid < 192) att_s[tid - 128] = att[tid - 128];
    {
        // stage ea -> bf16 fragments: thread covers edge e, 16 k's (2 chunks)
        const int e = tid & 127;
        const int c0 = (tid >> 7) * 2;         // chunks {0,1} or {2,3}
        const int ge = ge0 + e;
        float4 a = make_float4(0.f, 0.f, 0.f, 0.f), b = a, c = a, d4 = a;
        if (ge < E) {
            const float4* p = (const float4*)(eattr + (size_t)ge * 32 + c0 * 8);
            a = p[0]; b = p[1]; c = p[2]; d4 = p[3];
        }
        bf16x8 lo, hi;
        lo[0] = (short)f2bf(a.x); lo[1] = (short)f2bf(a.y); lo[2] = (short)f2bf(a.z); lo[3] = (short)f2bf(a.w);
        lo[4] = (short)f2bf(b.x); lo[5] = (short)f2bf(b.y); lo[6] = (short)f2bf(b.z); lo[7] = (short)f2bf(b.w);
        hi[0] = (short)f2bf(c.x); hi[1] = (short)f2bf(c.y); hi[2] = (short)f2bf(c.z); hi[3] = (short)f2bf(c.w);
        hi[4] = (short)f2bf(d4.x); hi[5] = (short)f2bf(d4.y); hi[6] = (short)f2bf(d4.z); hi[7] = (short)f2bf(d4.w);
        *(bf16x8*)&ea_frag[c0 + 0][e][0] = lo;
        *(bf16x8*)&ea_frag[c0 + 1][e][0] = hi;
    }

    const int w = tid >> 6, l = tid & 63;
    const int lo16 = l & 15, hi4 = l >> 4;

    // A-fragments: lane holds We[k=(hi4)*8+j][ch=ct*16+lo16], j=0..7
    bf16x8 afrag[4];
#pragma unroll
    for (int ct = 0; ct < 4; ++ct) {
#pragma unroll
        for (int j = 0; j < 8; ++j) {
            afrag[ct][j] = (short)f2bf(We[(hi4 * 8 + j) * 64 + ct * 16 + lo16]);
        }
    }
    __syncthreads();

    const int base_e0 = w * 32;   // wave covers edges [base_e0, base_e0+32)

    // B-fragments + MFMA: acc[et][ct]
    f32x4 acc[2][4];
#pragma unroll
    for (int et = 0; et < 2; ++et) {
        const int base_e = base_e0 + et * 16;
        bf16x8 bfrag = *(const bf16x8*)&ea_frag[hi4][base_e + lo16][0];
#pragma unroll
        for (int ct = 0; ct < 4; ++ct) {
            f32x4 zero = {0.f, 0.f, 0.f, 0.f};
            acc[et][ct] = __builtin_amdgcn_mfma_f32_16x16x32_bf16(afrag[ct], bfrag, zero, 0, 0, 0);
        }
    }

    // att values this lane needs: channels ct*16 + hi4*4 + r
    float attr_[4][4];
#pragma unroll
    for (int ct = 0; ct < 4; ++ct) {
        const float4 av = *(const float4*)&att_s[ct * 16 + hi4 * 4];
        attr_[ct][0] = av.x; attr_[ct][1] = av.y; attr_[ct][2] = av.z; attr_[ct][3] = av.w;
    }

    // epilogue per edge-tile
#pragma unroll
    for (int et = 0; et < 2; ++et) {
        const int eb = base_e0 + et * 16 + lo16;
        const int s = s_s[eb], d = d_s[eb];
        float part = 0.f;
#pragma unroll
        for (int ct = 0; ct < 4; ++ct) {
            const ushort4 xlv = *(const ushort4*)&xlb[(size_t)s * 64 + ct * 16 + hi4 * 4];
            const ushort4 xrv = *(const ushort4*)&xrb[(size_t)d * 64 + ct * 16 + hi4 * 4];
            const float xll[4] = {bf2f(xlv.x), bf2f(xlv.y), bf2f(xlv.z), bf2f(xlv.w)};
            const float xrr[4] = {bf2f(xrv.x), bf2f(xrv.y), bf2f(xrv.z), bf2f(xrv.w)};
#pragma unroll
            for (int r = 0; r < 4; ++r) {
                float zz = acc[et][ct][r] + xll[r] + xrr[r];
                zz = (zz > 0.f) ? zz : NEG_SLOPE * zz;
                part += attr_[ct][r] * zz;
            }
        }
        part += __shfl_xor(part, 16);
        part += __shfl_xor(part, 32);
        if (l < 16) {
            int ge = ge0 + base_e0 + et * 16 + l;
            if (ge < E) ex_sorted[sp_s[base_e0 + et * 16 + l]] = __expf(part);
        }
    }
}

// ---------- self-loop scores (bf16 x tables, fp32 GEMM — small) ----------
__global__ __launch_bounds__(256) void k_loop_score(
    const unsigned short* __restrict__ xlb, const unsigned short* __restrict__ xrb,
    const float* __restrict__ loop_attr,
    const float* __restrict__ We, const float* __restrict__ att,
    int n, float* __restrict__ ex_loop) {
    __shared__ float We_s[32 * 64];
    __shared__ float ea_T[32][68];
    __shared__ float att_s[64];

    const int tid = threadIdx.x;
    const int ge0 = blockIdx.x * 64;

    for (int i = tid; i < 2048; i += 256) We_s[i] = We[i];
    if (tid < 64) att_s[tid] = att[tid];
    {
        int e = tid & 63;
        int k0 = (tid >> 6) * 8;
        int ge = ge0 + e;
        float4 a = make_float4(0.f, 0.f, 0.f, 0.f), b = a;
        if (ge < n) {
            const float4* p = (const float4*)(loop_attr + (size_t)ge * 32 + k0);
            a = p[0]; b = p[1];
        }
        ea_T[k0 + 0][e] = a.x; ea_T[k0 + 1][e] = a.y; ea_T[k0 + 2][e] = a.z; ea_T[k0 + 3][e] = a.w;
        ea_T[k0 + 4][e] = b.x; ea_T[k0 + 5][e] = b.y; ea_T[k0 + 6][e] = b.z; ea_T[k0 + 7][e] = b.w;
    }
    __syncthreads();

    const int w = tid >> 6, l = tid & 63;
    const int t0 = (l & 15) * 4;
    const int e0 = w * 16 + (l >> 4) * 4;

    float z[4][4];
#pragma unroll
    for (int j = 0; j < 4; ++j)
#pragma unroll
        for (int i = 0; i < 4; ++i) z[j][i] = 0.f;

#pragma unroll 8
    for (int k = 0; k < 32; ++k) {
        const float4 ev = *(const float4*)&ea_T[k][e0];
        const float4 wv = *(const float4*)&We_s[k * 64 + t0];
        const float ee[4] = {ev.x, ev.y, ev.z, ev.w};
        const float ww[4] = {wv.x, wv.y, wv.z, wv.w};
#pragma unroll
        for (int j = 0; j < 4; ++j)
#pragma unroll
            for (int i = 0; i < 4; ++i) z[j][i] += ee[j] * ww[i];
    }

    const float4 av = *(const float4*)&att_s[t0];
    const float aa[4] = {av.x, av.y, av.z, av.w};
    float v[4];
#pragma unroll
    for (int j = 0; j < 4; ++j) {
        const int node = ge0 + e0 + j;
        const int nsafe = (node < n) ? node : 0;
        const ushort4 xlv = *(const ushort4*)&xlb[(size_t)nsafe * 64 + t0];
        const ushort4 xrv = *(const ushort4*)&xrb[(size_t)nsafe * 64 + t0];
        const float xll[4] = {bf2f(xlv.x), bf2f(xlv.y), bf2f(xlv.z), bf2f(xlv.w)};
        const float xrr[4] = {bf2f(xrv.x), bf2f(xrv.y), bf2f(xrv.z), bf2f(xrv.w)};
        float acc = 0.f;
#pragma unroll
        for (int i = 0; i < 4; ++i) {
            float zz = z[j][i] + xll[i] + xrr[i];
            zz = (zz > 0.f) ? zz : NEG_SLOPE * zz;
            acc += aa[i] * zz;
        }
        v[j] = acc;
    }
#pragma unroll
    for (int m = 1; m < 16; m <<= 1) {
#pragma unroll
        for (int j = 0; j < 4; ++j) v[j] += __shfl_xor(v[j], m);
    }
    if ((l & 15) == 0) {
#pragma unroll
        for (int j = 0; j < 4; ++j) {
            int node = ge0 + e0 + j;
            if (node < n) ex_loop[node] = __expf(v[j]);
        }
    }
}

// ---------- phase B: gather-side aggregation + epilogue ----------
template <bool FINAL>
__global__ __launch_bounds__(256, 2) void k_node_aggr(
    const float* __restrict__ xl, const int* __restrict__ start,
    const int* __restrict__ src_sorted, const float* __restrict__ ex_sorted,
    const float* __restrict__ ex_loop, const float* __restrict__ bias,
    const float* __restrict__ Wc, const float* __restrict__ bc,
    float* __restrict__ hout, int n) {
    int node = blockIdx.x * 4 + (threadIdx.x >> 6);
    int t = threadIdx.x & 63;
    if (node >= n) return;
    const int es = t >> 4;
    const int cg = t & 15;
    int a = start[node], b = start[node + 1];

    float4 acc = make_float4(0.f, 0.f, 0.f, 0.f);
    float den = 0.f;
    if (es == 0) {
        float exl = ex_loop[node];
        const float4 xv = *(const float4*)&xl[(size_t)node * 64 + cg * 4];
        acc.x = exl * xv.x; acc.y = exl * xv.y; acc.z = exl * xv.z; acc.w = exl * xv.w;
        den = exl;
    }
    for (int j = a; j < b; j += 64) {
        int m = b - j; if (m > 64) m = 64;
        int sj = 0; float exj = 0.f;
        if (t < m) { sj = src_sorted[j + t]; exj = ex_sorted[j + t]; }
        for (int i = 0; i < m; i += 16) {
            int idx[4]; float ex4[4]; const float4* p4[4];
#pragma unroll
            for (int q = 0; q < 4; ++q) {
                idx[q] = i + q * 4 + es;
                const int sq = __shfl(sj, idx[q]);
                ex4[q] = __shfl(exj, idx[q]);
                p4[q] = (const float4*)&xl[(size_t)sq * 64 + cg * 4];
            }
            float4 xv[4];
#pragma unroll
            for (int q = 0; q < 4; ++q)
                xv[q] = (idx[q] < m) ? *p4[q] : make_float4(0.f, 0.f, 0.f, 0.f);
#pragma unroll
            for (int q = 0; q < 4; ++q) {
                const float eq = (idx[q] < m) ? ex4[q] : 0.f;
                acc.x += eq * xv[q].x; acc.y += eq * xv[q].y;
                acc.z += eq * xv[q].z; acc.w += eq * xv[q].w;
                den += eq;
            }
        }
    }
#pragma unroll
    for (int mask = 16; mask <= 32; mask <<= 1) {
        acc.x += __shfl_xor(acc.x, mask);
        acc.y += __shfl_xor(acc.y, mask);
        acc.z += __shfl_xor(acc.z, mask);
        acc.w += __shfl_xor(acc.w, mask);
        den   += __shfl_xor(den, mask);
    }
    if (!FINAL) {
        if (es == 0) {
            const float4 bv = *(const float4*)&bias[cg * 4];
            float4 h;
            h.x = fmaxf(acc.x / den + bv.x, 0.f);
            h.y = fmaxf(acc.y / den + bv.y, 0.f);
            h.z = fmaxf(acc.z / den + bv.z, 0.f);
            h.w = fmaxf(acc.w / den + bv.w, 0.f);
            *(float4*)&hout[(size_t)node * 64 + cg * 4] = h;
        }
    } else {
        float v0 = 0.f, v1 = 0.f;
        if (es == 0) {
            const float4 bv = *(const float4*)&bias[cg * 4];
            const float h0 = fmaxf(acc.x / den + bv.x, 0.f);
            const float h1 = fmaxf(acc.y / den + bv.y, 0.f);
            const float h2 = fmaxf(acc.z / den + bv.z, 0.f);
            const float h3 = fmaxf(acc.w / den + bv.w, 0.f);
            const int c0 = cg * 4;
            v0 = h0 * Wc[(c0 + 0) * 2 + 0] + h1 * Wc[(c0 + 1) * 2 + 0]
               + h2 * Wc[(c0 + 2) * 2 + 0] + h3 * Wc[(c0 + 3) * 2 + 0];
            v1 = h0 * Wc[(c0 + 0) * 2 + 1] + h1 * Wc[(c0 + 1) * 2 + 1]
               + h2 * Wc[(c0 + 2) * 2 + 1] + h3 * Wc[(c0 + 3) * 2 + 1];
        }
#pragma unroll
        for (int mask = 1; mask <= 8; mask <<= 1) {
            v0 += __shfl_xor(v0, mask);
            v1 += __shfl_xor(v1, mask);
        }
        if (t == 0) {
            hout[(size_t)node * 2 + 0] = v0 + bc[0];
            hout[(size_t)node * 2 + 1] = v1 + bc[1];
        }
    }
}

extern "C" void kernel_launch(void* const* d_in, const int* in_sizes, int n_in,
                              void* d_out, int out_size, void* d_ws, size_t ws_size,
                              hipStream_t stream) {
    const float* x     = (const float*)d_in[0];
    const int*   ei    = (const int*)d_in[1];
    const float* eattr = (const float*)d_in[2];
    const float* Wl1 = (const float*)d_in[3];
    const float* bl1 = (const float*)d_in[4];
    const float* Wr1 = (const float*)d_in[5];
    const float* br1 = (const float*)d_in[6];
    const float* We1 = (const float*)d_in[7];
    const float* att1 = (const float*)d_in[8];
    const float* bias1 = (const float*)d_in[9];
    const float* Wl2 = (const float*)d_in[10];
    const float* bl2 = (const float*)d_in[11];
    const float* Wr2 = (const float*)d_in[12];
    const float* br2 = (const float*)d_in[13];
    const float* We2 = (const float*)d_in[14];
    const float* att2 = (const float*)d_in[15];
    const float* bias2 = (const float*)d_in[16];
    const float* Wc = (const float*)d_in[17];
    const float* bc = (const float*)d_in[18];

    const int N = in_sizes[0] / 128;
    const int E = in_sizes[1] / 2;
    const int* src = ei;
    const int* dst = ei + E;

    char* w = (char*)d_ws;
    auto alloc = [&](size_t bytes) {
        char* p = w;
        w += (bytes + 255) & ~(size_t)255;
        return p;
    };
    float*          xl         = (float*)alloc((size_t)N * 64 * 4);
    unsigned short* xlb        = (unsigned short*)alloc((size_t)N * 64 * 2);
    unsigned short* xrb        = (unsigned short*)alloc((size_t)N * 64 * 2);
    float*          hbuf       = (float*)alloc((size_t)N * 64 * 4);
    float*          loop_attr  = (float*)alloc((size_t)N * 32 * 4);
    float*          ex_loop    = (float*)alloc((size_t)N * 4);
    int*            deg_i      = (int*)alloc((size_t)N * 4);
    int*            start      = (int*)alloc((size_t)(N + 1) * 4);
    int*            cursor     = (int*)alloc((size_t)N * 4);
    int*            csum       = (int*)alloc(256 * 4);
    int*            perm       = (int*)alloc((size_t)E * 4);
    int*            src_sorted = (int*)alloc((size_t)E * 4);
    int*            sortpos    = (int*)alloc((size_t)E * 4);
    float*          ex_sorted  = (float*)alloc((size_t)E * 4);

    const int THREADS = 256;
    const int score_blocks = (E + 127) / 128;
    const int loop_blocks = (N + 63) / 64;
    const int node4_blocks = (N + 3) / 4;
    const int edge_blocks = (E + THREADS - 1) / THREADS;
    const int nchunks = (N + 1023) / 1024;

    // ---- CSR by dst (shared by both layers) ----
    hipMemsetAsync(deg_i, 0, (size_t)N * 4, stream);
    hipMemsetAsync(cursor, 0, (size_t)N * 4, stream);
    k_hist<<<edge_blocks, THREADS, 0, stream>>>(dst, E, deg_i);
    k_scan_chunk<<<nchunks, 1024, 0, stream>>>(deg_i, start, csum, N);
    k_scan_top<<<1, 64, 0, stream>>>(csum, nchunks, start, N);
    k_scan_apply<<<(N + THREADS - 1) / THREADS, THREADS, 0, stream>>>(start, csum, N);
    k_fill<<<edge_blocks, THREADS, 0, stream>>>(src, dst, E, start, cursor,
                                                perm, src_sorted, sortpos);
    k_loop_csr<<<node4_blocks, THREADS, 0, stream>>>(eattr, perm, start, loop_attr, N);

    // ---- layer 1 ----
    k_node_transform<128><<<node4_blocks, THREADS, 0, stream>>>(x, Wl1, bl1, Wr1, br1,
                                                                xl, xlb, xrb, N);
    k_edge_score<<<score_blocks, THREADS, 0, stream>>>(
        xlb, xrb, eattr, We1, att1, src, dst, sortpos, E, ex_sorted);
    k_loop_score<<<loop_blocks, THREADS, 0, stream>>>(xlb, xrb, loop_attr, We1, att1, N, ex_loop);
    k_node_aggr<false><<<node4_blocks, THREADS, 0, stream>>>(xl, start, src_sorted, ex_sorted,
                                                             ex_loop, bias1, Wc, bc, hbuf, N);

    // ---- layer 2 ----
    k_node_transform<64><<<node4_blocks, THREADS, 0, stream>>>(hbuf, Wl2, bl2, Wr2, br2,
                                                               xl, xlb, xrb, N);
    k_loop_score<<<loop_blocks, THREADS, 0, stream>>>(xlb, xrb, loop_attr, We2, att2, N, ex_loop);
    k_edge_score<<<score_blocks, THREADS, 0, stream>>>(
        xlb, xrb, eattr, We2, att2, src, dst, sortpos, E, ex_sorted);
    k_node_aggr<true><<<node4_blocks, THREADS, 0, stream>>>(xl, start, src_sorted, ex_sorted,
                                                            ex_loop, bias2, Wc, bc, (float*)d_out, N);
}

// Round 13
// 739.700 us; speedup vs baseline: 1.0890x; 1.0890x over previous
//
#include <hip/hip_runtime.h>
#include <hip/hip_bf16.h>

#define NEG_SLOPE 0.2f

__device__ __forceinline__ float bf2f(unsigned short u) {
    return __uint_as_float((unsigned)u << 16);
}
__device__ __forceinline__ float bflo(unsigned u) { return __uint_as_float(u << 16); }
__device__ __forceinline__ float bfhi(unsigned u) { return __uint_as_float(u & 0xFFFF0000u); }
__device__ __forceinline__ unsigned short f2bf(float f) {
    unsigned b = __float_as_uint(f);
    return (unsigned short)((b + 0x7FFFu + ((b >> 16) & 1u)) >> 16);
}

// ---------- CSR build ----------
__global__ void k_hist(const int* __restrict__ dst, int E, int* __restrict__ deg) {
    int e = blockIdx.x * 256 + threadIdx.x;
    if (e < E) atomicAdd(&deg[dst[e]], 1);
}

__global__ __launch_bounds__(1024) void k_scan_chunk(const int* __restrict__ deg,
                                                     int* __restrict__ start,
                                                     int* __restrict__ csum, int n) {
    __shared__ int wsum[16];
    const int lane = threadIdx.x & 63;
    const int w = threadIdx.x >> 6;
    int i = blockIdx.x * 1024 + (int)threadIdx.x;
    int v = (i < n) ? deg[i] : 0;
    int s = v;
#pragma unroll
    for (int o = 1; o < 64; o <<= 1) {
        int u = __shfl_up(s, o);
        if (lane >= o) s += u;
    }
    if (lane == 63) wsum[w] = s;
    __syncthreads();
    if (w == 0) {
        int ws = (lane < 16) ? wsum[lane] : 0;
#pragma unroll
        for (int o = 1; o < 16; o <<= 1) {
            int u = __shfl_up(ws, o);
            if (lane >= o) ws += u;
        }
        if (lane < 16) wsum[lane] = ws;
    }
    __syncthreads();
    int woff = (w == 0) ? 0 : wsum[w - 1];
    int incl = s + woff;
    if (i < n) start[i] = incl - v;
    if (threadIdx.x == 1023) csum[blockIdx.x] = incl;
}

__global__ void k_scan_top(int* __restrict__ csum, int nch, int* __restrict__ start, int n) {
    int t = threadIdx.x;
    int v = (t < nch) ? csum[t] : 0;
    int s = v;
#pragma unroll
    for (int o = 1; o < 64; o <<= 1) {
        int u = __shfl_up(s, o);
        if (t >= o) s += u;
    }
    if (t < nch) csum[t] = s - v;
    if (t == 63) start[n] = s;
}

__global__ void k_scan_apply(int* __restrict__ start, const int* __restrict__ csum, int n) {
    int i = blockIdx.x * 256 + threadIdx.x;
    if (i < n) start[i] += csum[i >> 10];
}

__global__ void k_fill(const int* __restrict__ src, const int* __restrict__ dst, int E,
                       const int* __restrict__ start, int* __restrict__ cursor,
                       int* __restrict__ perm, int* __restrict__ src_sorted,
                       int* __restrict__ sortpos) {
    int e = blockIdx.x * 256 + threadIdx.x;
    if (e >= E) return;
    int d = dst[e];
    int idx = start[d] + atomicAdd(&cursor[d], 1);
    perm[idx] = e;
    src_sorted[idx] = src[e];
    sortpos[e] = idx;
}

// ---------- self-loop attr: gather-side segment mean, 16 rows in flight ----------
__global__ __launch_bounds__(256) void k_loop_csr(
    const float* __restrict__ eattr, const int* __restrict__ perm,
    const int* __restrict__ start, float* __restrict__ loop_attr, int n) {
    int node = blockIdx.x * 4 + (threadIdx.x >> 6);
    int t = threadIdx.x & 63;
    if (node >= n) return;
    int a = start[node], b = start[node + 1];
    int g = t >> 3, gl = t & 7;
    float4 acc = make_float4(0.f, 0.f, 0.f, 0.f);
    int j = a + g;
    for (; j + 8 < b; j += 16) {
        int e1 = perm[j];
        int e2 = perm[j + 8];
        const float4 v1 = *(const float4*)&eattr[(size_t)e1 * 32 + gl * 4];
        const float4 v2 = *(const float4*)&eattr[(size_t)e2 * 32 + gl * 4];
        acc.x += v1.x + v2.x; acc.y += v1.y + v2.y;
        acc.z += v1.z + v2.z; acc.w += v1.w + v2.w;
    }
    if (j < b) {
        int e = perm[j];
        const float4 v = *(const float4*)&eattr[(size_t)e * 32 + gl * 4];
        acc.x += v.x; acc.y += v.y; acc.z += v.z; acc.w += v.w;
    }
#pragma unroll
    for (int mask = 8; mask <= 32; mask <<= 1) {
        acc.x += __shfl_xor(acc.x, mask);
        acc.y += __shfl_xor(acc.y, mask);
        acc.z += __shfl_xor(acc.z, mask);
        acc.w += __shfl_xor(acc.w, mask);
    }
    if (t < 8) {
        float deg = fmaxf((float)(b - a), 1.f);
        float4 o = make_float4(acc.x / deg, acc.y / deg, acc.z / deg, acc.w / deg);
        *(float4*)&loop_attr[(size_t)node * 32 + gl * 4] = o;
    }
}

// ---------- node transform: bf16 tables only ----------
template <int DIN>
__global__ void k_node_transform(const float* __restrict__ h,
                                 const float* __restrict__ Wl, const float* __restrict__ bl,
                                 const float* __restrict__ Wr, const float* __restrict__ br,
                                 unsigned short* __restrict__ xlb,
                                 unsigned short* __restrict__ xrb, int n) {
    __shared__ float hs[4][DIN];
    int node0 = blockIdx.x * 4;
    int tid = threadIdx.x;
    for (int idx = tid; idx < 4 * DIN; idx += 256) {
        int ln = idx / DIN, k = idx % DIN;
        int node = node0 + ln;
        hs[ln][k] = (node < n) ? h[(long long)node * DIN + k] : 0.f;
    }
    __syncthreads();
    int ln = tid >> 6;
    int j = tid & 63;
    int node = node0 + ln;
    if (node >= n) return;
    float al = bl[j], ar = br[j];
#pragma unroll 8
    for (int k = 0; k < DIN; ++k) {
        float hv = hs[ln][k];
        al += hv * Wl[k * 64 + j];
        ar += hv * Wr[k * 64 + j];
    }
    xlb[(long long)node * 64 + j] = f2bf(al);
    xrb[(long long)node * 64 + j] = f2bf(ar);
}

// ---------- phase A: edge scores, streaming order, bf16 gather tables ----------
// (reverted to R11 — proven 148 us; MFMA variant removed: duration was
//  gather-request-bound, not VALU-bound)
__global__ __launch_bounds__(256, 2) void k_edge_score(
    const unsigned short* __restrict__ xlb, const unsigned short* __restrict__ xrb,
    const float* __restrict__ eattr,
    const float* __restrict__ We, const float* __restrict__ att,
    const int* __restrict__ src, const int* __restrict__ dst,
    const int* __restrict__ sortpos, int E,
    float* __restrict__ ex_sorted) {
    __shared__ __align__(16) float We_s[32 * 64];
    __shared__ __align__(16) float ea_T[32][132];
    __shared__ float att_s[64];
    __shared__ int s_s[128], d_s[128], sp_s[128];

    const int tid = threadIdx.x;
    const int ge0 = blockIdx.x * 128;

    if (tid < 128) {
        int ge = ge0 + tid;
        bool ok = ge < E;
        s_s[tid] = ok ? src[ge] : 0;
        d_s[tid] = ok ? dst[ge] : 0;
        sp_s[tid] = ok ? sortpos[ge] : 0;
    }
    {
        const int e = tid & 127;
        const int kc = (tid >> 7) * 16;
        const int ge = ge0 + e;
        float4 a = make_float4(0.f, 0.f, 0.f, 0.f), b = a, c = a, d4 = a;
        if (ge < E) {
            const float4* p = (const float4*)(eattr + (size_t)ge * 32 + kc);
            a = p[0]; b = p[1]; c = p[2]; d4 = p[3];
        }
        ea_T[kc + 0][e] = a.x;  ea_T[kc + 1][e] = a.y;  ea_T[kc + 2][e] = a.z;  ea_T[kc + 3][e] = a.w;
        ea_T[kc + 4][e] = b.x;  ea_T[kc + 5][e] = b.y;  ea_T[kc + 6][e] = b.z;  ea_T[kc + 7][e] = b.w;
        ea_T[kc + 8][e] = c.x;  ea_T[kc + 9][e] = c.y;  ea_T[kc + 10][e] = c.z; ea_T[kc + 11][e] = c.w;
        ea_T[kc + 12][e] = d4.x; ea_T[kc + 13][e] = d4.y; ea_T[kc + 14][e] = d4.z; ea_T[kc + 15][e] = d4.w;
    }
    for (int i = tid; i < 2048; i += 256) We_s[i] = We[i];
    if (tid < 64) att_s[tid] = att[tid];
    __syncthreads();

    const int w = tid >> 6, l = tid & 63;
    const int t0 = (l & 15) * 4;            // channel group
    const int e0 = w * 32 + (l >> 4) * 8;   // edge group (8 edges)

    // issue all gathers first (8B/lane bf16) — hide under the GEMM
    ushort4 xlv[8], xrv[8];
#pragma unroll
    for (int j = 0; j < 8; ++j) {
        const int eb = e0 + j;
        xlv[j] = *(const ushort4*)&xlb[(size_t)s_s[eb] * 64 + t0];
        xrv[j] = *(const ushort4*)&xrb[(size_t)d_s[eb] * 64 + t0];
    }

    float z[8][4];
#pragma unroll
    for (int j = 0; j < 8; ++j)
#pragma unroll
        for (int i = 0; i < 4; ++i) z[j][i] = 0.f;

#pragma unroll 4
    for (int k = 0; k < 32; ++k) {
        const float4 ev0 = *(const float4*)&ea_T[k][e0];
        const float4 ev1 = *(const float4*)&ea_T[k][e0 + 4];
        const float4 wv = *(const float4*)&We_s[k * 64 + t0];
        const float ee[8] = {ev0.x, ev0.y, ev0.z, ev0.w, ev1.x, ev1.y, ev1.z, ev1.w};
        const float ww[4] = {wv.x, wv.y, wv.z, wv.w};
#pragma unroll
        for (int j = 0; j < 8; ++j)
#pragma unroll
            for (int i = 0; i < 4; ++i) z[j][i] += ee[j] * ww[i];
    }

    const float4 av = *(const float4*)&att_s[t0];
    const float aa[4] = {av.x, av.y, av.z, av.w};
    float v[8];
#pragma unroll
    for (int j = 0; j < 8; ++j) {
        const float xll[4] = {bf2f(xlv[j].x), bf2f(xlv[j].y), bf2f(xlv[j].z), bf2f(xlv[j].w)};
        const float xrr[4] = {bf2f(xrv[j].x), bf2f(xrv[j].y), bf2f(xrv[j].z), bf2f(xrv[j].w)};
        float acc = 0.f;
#pragma unroll
        for (int i = 0; i < 4; ++i) {
            float zz = z[j][i] + xll[i] + xrr[i];
            zz = (zz > 0.f) ? zz : NEG_SLOPE * zz;
            acc += aa[i] * zz;
        }
        v[j] = acc;
    }
#pragma unroll
    for (int m = 1; m < 16; m <<= 1) {
#pragma unroll
        for (int j = 0; j < 8; ++j) v[j] += __shfl_xor(v[j], m);
    }
    if ((l & 15) == 0) {
#pragma unroll
        for (int j = 0; j < 8; ++j) {
            int ge = ge0 + e0 + j;
            if (ge < E) ex_sorted[sp_s[e0 + j]] = __expf(v[j]);
        }
    }
}

// ---------- self-loop scores (bf16 x tables) ----------
__global__ __launch_bounds__(256) void k_loop_score(
    const unsigned short* __restrict__ xlb, const unsigned short* __restrict__ xrb,
    const float* __restrict__ loop_attr,
    const float* __restrict__ We, const float* __restrict__ att,
    int n, float* __restrict__ ex_loop) {
    __shared__ float We_s[32 * 64];
    __shared__ float ea_T[32][68];
    __shared__ float att_s[64];

    const int tid = threadIdx.x;
    const int ge0 = blockIdx.x * 64;

    for (int i = tid; i < 2048; i += 256) We_s[i] = We[i];
    if (tid < 64) att_s[tid] = att[tid];
    {
        int e = tid & 63;
        int k0 = (tid >> 6) * 8;
        int ge = ge0 + e;
        float4 a = make_float4(0.f, 0.f, 0.f, 0.f), b = a;
        if (ge < n) {
            const float4* p = (const float4*)(loop_attr + (size_t)ge * 32 + k0);
            a = p[0]; b = p[1];
        }
        ea_T[k0 + 0][e] = a.x; ea_T[k0 + 1][e] = a.y; ea_T[k0 + 2][e] = a.z; ea_T[k0 + 3][e] = a.w;
        ea_T[k0 + 4][e] = b.x; ea_T[k0 + 5][e] = b.y; ea_T[k0 + 6][e] = b.z; ea_T[k0 + 7][e] = b.w;
    }
    __syncthreads();

    const int w = tid >> 6, l = tid & 63;
    const int t0 = (l & 15) * 4;
    const int e0 = w * 16 + (l >> 4) * 4;

    float z[4][4];
#pragma unroll
    for (int j = 0; j < 4; ++j)
#pragma unroll
        for (int i = 0; i < 4; ++i) z[j][i] = 0.f;

#pragma unroll 8
    for (int k = 0; k < 32; ++k) {
        const float4 ev = *(const float4*)&ea_T[k][e0];
        const float4 wv = *(const float4*)&We_s[k * 64 + t0];
        const float ee[4] = {ev.x, ev.y, ev.z, ev.w};
        const float ww[4] = {wv.x, wv.y, wv.z, wv.w};
#pragma unroll
        for (int j = 0; j < 4; ++j)
#pragma unroll
            for (int i = 0; i < 4; ++i) z[j][i] += ee[j] * ww[i];
    }

    const float4 av = *(const float4*)&att_s[t0];
    const float aa[4] = {av.x, av.y, av.z, av.w};
    float v[4];
#pragma unroll
    for (int j = 0; j < 4; ++j) {
        const int node = ge0 + e0 + j;
        const int nsafe = (node < n) ? node : 0;
        const ushort4 xlv = *(const ushort4*)&xlb[(size_t)nsafe * 64 + t0];
        const ushort4 xrv = *(const ushort4*)&xrb[(size_t)nsafe * 64 + t0];
        const float xll[4] = {bf2f(xlv.x), bf2f(xlv.y), bf2f(xlv.z), bf2f(xlv.w)};
        const float xrr[4] = {bf2f(xrv.x), bf2f(xrv.y), bf2f(xrv.z), bf2f(xrv.w)};
        float acc = 0.f;
#pragma unroll
        for (int i = 0; i < 4; ++i) {
            float zz = z[j][i] + xll[i] + xrr[i];
            zz = (zz > 0.f) ? zz : NEG_SLOPE * zz;
            acc += aa[i] * zz;
        }
        v[j] = acc;
    }
#pragma unroll
    for (int m = 1; m < 16; m <<= 1) {
#pragma unroll
        for (int j = 0; j < 4; ++j) v[j] += __shfl_xor(v[j], m);
    }
    if ((l & 15) == 0) {
#pragma unroll
        for (int j = 0; j < 4; ++j) {
            int node = ge0 + e0 + j;
            if (node < n) ex_loop[node] = __expf(v[j]);
        }
    }
}

// ---------- phase B: gather-side aggregation, bf16 rows ----------
// 8 edge slots x 8-channel groups; ONE 16B uint4 load per row-slice
// (128B bf16 row = 2 x 64B granules, half of fp32); 16 rows in flight.
template <bool FINAL>
__global__ __launch_bounds__(256, 2) void k_node_aggr(
    const unsigned short* __restrict__ xlb, const int* __restrict__ start,
    const int* __restrict__ src_sorted, const float* __restrict__ ex_sorted,
    const float* __restrict__ ex_loop, const float* __restrict__ bias,
    const float* __restrict__ Wc, const float* __restrict__ bc,
    float* __restrict__ hout, int n) {
    int node = blockIdx.x * 4 + (threadIdx.x >> 6);
    int t = threadIdx.x & 63;
    if (node >= n) return;
    const int g = t >> 3;    // edge slot 0..7
    const int c8 = t & 7;    // channel group: channels c8*8 .. c8*8+7
    int a = start[node], b = start[node + 1];

    float acc[8] = {0.f, 0.f, 0.f, 0.f, 0.f, 0.f, 0.f, 0.f};
    float den = 0.f;
    if (g == 0) {
        const float exl = ex_loop[node];
        const uint4 q = *(const uint4*)&xlb[(size_t)node * 64 + c8 * 8];
        acc[0] = exl * bflo(q.x); acc[1] = exl * bfhi(q.x);
        acc[2] = exl * bflo(q.y); acc[3] = exl * bfhi(q.y);
        acc[4] = exl * bflo(q.z); acc[5] = exl * bfhi(q.z);
        acc[6] = exl * bflo(q.w); acc[7] = exl * bfhi(q.w);
        den = exl;
    }
    for (int j = a; j < b; j += 64) {
        int m = b - j; if (m > 64) m = 64;
        int sj = 0; float exj = 0.f;
        if (t < m) { sj = src_sorted[j + t]; exj = ex_sorted[j + t]; }
        for (int i = 0; i < m; i += 16) {
            const int i0 = i + g, i1 = i + 8 + g;
            const int s0 = __shfl(sj, i0); const float e0 = __shfl(exj, i0);
            const int s1 = __shfl(sj, i1); const float e1 = __shfl(exj, i1);
            uint4 q0 = *(const uint4*)&xlb[(size_t)s0 * 64 + c8 * 8];
            uint4 q1 = *(const uint4*)&xlb[(size_t)s1 * 64 + c8 * 8];
            if (i0 < m) {
                acc[0] += e0 * bflo(q0.x); acc[1] += e0 * bfhi(q0.x);
                acc[2] += e0 * bflo(q0.y); acc[3] += e0 * bfhi(q0.y);
                acc[4] += e0 * bflo(q0.z); acc[5] += e0 * bfhi(q0.z);
                acc[6] += e0 * bflo(q0.w); acc[7] += e0 * bfhi(q0.w);
                den += e0;
            }
            if (i1 < m) {
                acc[0] += e1 * bflo(q1.x); acc[1] += e1 * bfhi(q1.x);
                acc[2] += e1 * bflo(q1.y); acc[3] += e1 * bfhi(q1.y);
                acc[4] += e1 * bflo(q1.z); acc[5] += e1 * bfhi(q1.z);
                acc[6] += e1 * bflo(q1.w); acc[7] += e1 * bfhi(q1.w);
                den += e1;
            }
        }
    }
    // reduce across edge slots (lane bits 3,4,5)
#pragma unroll
    for (int mask = 8; mask <= 32; mask <<= 1) {
#pragma unroll
        for (int r = 0; r < 8; ++r) acc[r] += __shfl_xor(acc[r], mask);
        den += __shfl_xor(den, mask);
    }
    if (!FINAL) {
        if (g == 0) {
            float h[8];
#pragma unroll
            for (int r = 0; r < 8; ++r)
                h[r] = fmaxf(acc[r] / den + bias[c8 * 8 + r], 0.f);
            float4 o0 = make_float4(h[0], h[1], h[2], h[3]);
            float4 o1 = make_float4(h[4], h[5], h[6], h[7]);
            *(float4*)&hout[(size_t)node * 64 + c8 * 8] = o0;
            *(float4*)&hout[(size_t)node * 64 + c8 * 8 + 4] = o1;
        }
    } else {
        float v0 = 0.f, v1 = 0.f;
        if (g == 0) {
#pragma unroll
            for (int r = 0; r < 8; ++r) {
                const int ch = c8 * 8 + r;
                const float h = fmaxf(acc[r] / den + bias[ch], 0.f);
                v0 += h * Wc[ch * 2 + 0];
                v1 += h * Wc[ch * 2 + 1];
            }
        }
#pragma unroll
        for (int mask = 1; mask <= 4; mask <<= 1) {
            v0 += __shfl_xor(v0, mask);
            v1 += __shfl_xor(v1, mask);
        }
        if (t == 0) {
            hout[(size_t)node * 2 + 0] = v0 + bc[0];
            hout[(size_t)node * 2 + 1] = v1 + bc[1];
        }
    }
}

extern "C" void kernel_launch(void* const* d_in, const int* in_sizes, int n_in,
                              void* d_out, int out_size, void* d_ws, size_t ws_size,
                              hipStream_t stream) {
    const float* x     = (const float*)d_in[0];
    const int*   ei    = (const int*)d_in[1];
    const float* eattr = (const float*)d_in[2];
    const float* Wl1 = (const float*)d_in[3];
    const float* bl1 = (const float*)d_in[4];
    const float* Wr1 = (const float*)d_in[5];
    const float* br1 = (const float*)d_in[6];
    const float* We1 = (const float*)d_in[7];
    const float* att1 = (const float*)d_in[8];
    const float* bias1 = (const float*)d_in[9];
    const float* Wl2 = (const float*)d_in[10];
    const float* bl2 = (const float*)d_in[11];
    const float* Wr2 = (const float*)d_in[12];
    const float* br2 = (const float*)d_in[13];
    const float* We2 = (const float*)d_in[14];
    const float* att2 = (const float*)d_in[15];
    const float* bias2 = (const float*)d_in[16];
    const float* Wc = (const float*)d_in[17];
    const float* bc = (const float*)d_in[18];

    const int N = in_sizes[0] / 128;
    const int E = in_sizes[1] / 2;
    const int* src = ei;
    const int* dst = ei + E;

    char* w = (char*)d_ws;
    auto alloc = [&](size_t bytes) {
        char* p = w;
        w += (bytes + 255) & ~(size_t)255;
        return p;
    };
    unsigned short* xlb        = (unsigned short*)alloc((size_t)N * 64 * 2);
    unsigned short* xrb        = (unsigned short*)alloc((size_t)N * 64 * 2);
    float*          hbuf       = (float*)alloc((size_t)N * 64 * 4);
    float*          loop_attr  = (float*)alloc((size_t)N * 32 * 4);
    float*          ex_loop    = (float*)alloc((size_t)N * 4);
    int*            deg_i      = (int*)alloc((size_t)N * 4);
    int*            start      = (int*)alloc((size_t)(N + 1) * 4);
    int*            cursor     = (int*)alloc((size_t)N * 4);
    int*            csum       = (int*)alloc(256 * 4);
    int*            perm       = (int*)alloc((size_t)E * 4);
    int*            src_sorted = (int*)alloc((size_t)E * 4);
    int*            sortpos    = (int*)alloc((size_t)E * 4);
    float*          ex_sorted  = (float*)alloc((size_t)E * 4);

    const int THREADS = 256;
    const int score_blocks = (E + 127) / 128;
    const int loop_blocks = (N + 63) / 64;
    const int node4_blocks = (N + 3) / 4;
    const int edge_blocks = (E + THREADS - 1) / THREADS;
    const int nchunks = (N + 1023) / 1024;

    // ---- CSR by dst (shared by both layers) ----
    hipMemsetAsync(deg_i, 0, (size_t)N * 4, stream);
    hipMemsetAsync(cursor, 0, (size_t)N * 4, stream);
    k_hist<<<edge_blocks, THREADS, 0, stream>>>(dst, E, deg_i);
    k_scan_chunk<<<nchunks, 1024, 0, stream>>>(deg_i, start, csum, N);
    k_scan_top<<<1, 64, 0, stream>>>(csum, nchunks, start, N);
    k_scan_apply<<<(N + THREADS - 1) / THREADS, THREADS, 0, stream>>>(start, csum, N);
    k_fill<<<edge_blocks, THREADS, 0, stream>>>(src, dst, E, start, cursor,
                                                perm, src_sorted, sortpos);
    k_loop_csr<<<node4_blocks, THREADS, 0, stream>>>(eattr, perm, start, loop_attr, N);

    // ---- layer 1 ----
    k_node_transform<128><<<node4_blocks, THREADS, 0, stream>>>(x, Wl1, bl1, Wr1, br1,
                                                                xlb, xrb, N);
    k_edge_score<<<score_blocks, THREADS, 0, stream>>>(
        xlb, xrb, eattr, We1, att1, src, dst, sortpos, E, ex_sorted);
    k_loop_score<<<loop_blocks, THREADS, 0, stream>>>(xlb, xrb, loop_attr, We1, att1, N, ex_loop);
    k_node_aggr<false><<<node4_blocks, THREADS, 0, stream>>>(xlb, start, src_sorted, ex_sorted,
                                                             ex_loop, bias1, Wc, bc, hbuf, N);

    // ---- layer 2 ----
    k_node_transform<64><<<node4_blocks, THREADS, 0, stream>>>(hbuf, Wl2, bl2, Wr2, br2,
                                                               xlb, xrb, N);
    k_loop_score<<<loop_blocks, THREADS, 0, stream>>>(xlb, xrb, loop_attr, We2, att2, N, ex_loop);
    k_edge_score<<<score_blocks, THREADS, 0, stream>>>(
        xlb, xrb, eattr, We2, att2, src, dst, sortpos, E, ex_sorted);
    k_node_aggr<true><<<node4_blocks, THREADS, 0, stream>>>(xlb, start, src_sorted, ex_sorted,
                                                            ex_loop, bias2, Wc, bc, (float*)d_out, N);
}